// Round 10
// baseline (236.166 us; speedup 1.0000x reference)
//
#include <hip/hip_runtime.h>

#define NN     30000
#define NNZE   480000
#define NPART  8
#define PROWS  (NN / NPART)      // 3750, exact
#define NCHUNK 32
#define CH_E   (NNZE / NCHUNK)   // 15000, exact
#define HBIN   (NN / 2)          // 15000 bins per half (60000 B LDS)
#define SCB    118               // ceil(30000/256)

using s8 = __attribute__((ext_vector_type(8))) short;  // 8 bf16 = 4 VGPRs
using f4 = __attribute__((ext_vector_type(4))) float;

__device__ __forceinline__ unsigned short f2bf(float x) {
    unsigned int u = __float_as_uint(x);
    u += 0x7fff + ((u >> 16) & 1);          // round-to-nearest-even
    return (unsigned short)(u >> 16);
}
__device__ __forceinline__ float bf2f(unsigned short h) {
    return __uint_as_float(((unsigned int)h) << 16);
}
__device__ __forceinline__ float bflo(unsigned int z) {
    return __uint_as_float(z << 16);
}
__device__ __forceinline__ float bfhi(unsigned int z) {
    return __uint_as_float(z & 0xffff0000u);
}
__device__ __forceinline__ int2 nt_pair(const int2* p) {
    long long v = __builtin_nontemporal_load((const long long*)p);
    int2 r; r.x = (int)(unsigned int)v; r.y = (int)(v >> 32); return r;
}
__device__ __forceinline__ unsigned long long nt_u64(const void* p) {
    return __builtin_nontemporal_load((const unsigned long long*)p);
}

// ---------------------------------------------------------------------------
// fused prep: feat->bf16 conversion, weight transpose->bf16, bias sums
// ---------------------------------------------------------------------------
#define FEAT4   (NN * 64 / 4)              // 480000 float4 groups per feat
#define PREP_W0 (2 * FEAT4)                // 960000
#define PREP_W1 (PREP_W0 + 98688)          // wprep range
__global__ __launch_bounds__(256) void prep_kernel(
    const float* __restrict__ lf, const float* __restrict__ rf,
    const float* __restrict__ W1, const float* __restrict__ W2,
    const float* __restrict__ W3, const float* __restrict__ W4,
    const float* __restrict__ b1, const float* __restrict__ b2,
    const float* __restrict__ b3, const float* __restrict__ b4,
    unsigned short* __restrict__ lfb, unsigned short* __restrict__ rfb,
    unsigned short* __restrict__ Wt1, unsigned short* __restrict__ Wt2,
    float* __restrict__ bias1, float* __restrict__ bias2)
{
    int i = blockIdx.x * 256 + threadIdx.x;
    if (i < PREP_W0) {
        const float* src = (i < FEAT4) ? lf : rf;
        unsigned short* dst = (i < FEAT4) ? lfb : rfb;
        int j = (i < FEAT4) ? i : i - FEAT4;
        float4 v = ((const float4*)src)[j];
        ushort4 o;
        o.x = f2bf(v.x); o.y = f2bf(v.y); o.z = f2bf(v.z); o.w = f2bf(v.w);
        ((ushort4*)dst)[j] = o;
    } else if (i < PREP_W1) {
        int j = i - PREP_W0;
        if (j < 32768) {                       // Wt1: [256][128]
            int n = j >> 7, k = j & 127;
            float v = (k < 64) ? W1[(size_t)k * 256 + n] : W2[(size_t)(k - 64) * 256 + n];
            Wt1[j] = f2bf(v);
        } else if (j < 32768 + 65536) {        // Wt2: [128][512]
            int q = j - 32768;
            int n = q >> 9, k = q & 511;
            float v = (k < 256) ? W3[(size_t)k * 128 + n] : W4[(size_t)(k - 256) * 128 + n];
            Wt2[q] = f2bf(v);
        } else if (j < 98304 + 256) {
            int n = j - 98304; bias1[n] = b1[n] + b2[n];
        } else if (j < 98560 + 128) {
            int n = j - 98560; bias2[n] = b3[n] + b4[n];
        }
    }
}

// ---------------------------------------------------------------------------
// LDS-histogram count + local rank. 128 blocks = side(2) x chunk(32) x half(2).
// ---------------------------------------------------------------------------
__global__ __launch_bounds__(256) void count_rank_kernel(
    const int* __restrict__ rows, const int* __restrict__ cols,
    int* __restrict__ histP,
    unsigned short* __restrict__ rank_r, unsigned short* __restrict__ rank_c)
{
    int b = blockIdx.x;
    int side  = b >> 6;
    int chunk = (b & 63) >> 1;
    int half  = b & 1;
    const int* keys = side ? cols : rows;
    unsigned short* rank = side ? rank_c : rank_r;
    int binlo = half * HBIN;

    __shared__ int h[HBIN];                  // 60000 B
    for (int i = threadIdx.x; i < HBIN; i += 256) h[i] = 0;
    __syncthreads();

    int e0 = chunk * CH_E;
    for (int e = e0 + threadIdx.x; e < e0 + CH_E; e += 256) {
        int k = __builtin_nontemporal_load(keys + e) - binlo;
        if ((unsigned)k < (unsigned)HBIN)
            rank[e] = (unsigned short)atomicAdd(&h[k], 1);
    }
    __syncthreads();

    int* dst = histP + ((size_t)(side * NCHUNK + chunk)) * NN + binlo;
    for (int i = threadIdx.x; i < HBIN; i += 256)
        __builtin_nontemporal_store(h[i], dst + i);
}

// ---------------------------------------------------------------------------
// scanP: per-bin exclusive prefix over 32 chunk histograms (in place),
// then local 256-wide scan -> rp/cp + totals
// ---------------------------------------------------------------------------
__global__ __launch_bounds__(256) void scanP_kernel(
    int* __restrict__ histP,
    int* __restrict__ rp, int* __restrict__ cp, int* __restrict__ totals)
{
    int b = blockIdx.x;
    int side = (b >= SCB) ? 1 : 0;
    int lb = side ? b - SCB : b;
    int t = threadIdx.x;
    int bin = lb * 256 + t;

    int run = 0;
    if (bin < NN) {
        int* base = histP + (size_t)side * NCHUNK * NN + bin;
#pragma unroll 4
        for (int c = 0; c < NCHUNK; ++c) {
            int v = base[(size_t)c * NN];
            base[(size_t)c * NN] = run;
            run += v;
        }
    }
    __shared__ int s[256];
    s[t] = run;
    __syncthreads();
#pragma unroll
    for (int off = 1; off < 256; off <<= 1) {
        int u = (t >= off) ? s[t - off] : 0;
        __syncthreads();
        s[t] += u;
        __syncthreads();
    }
    if (bin < NN) (side ? cp : rp)[bin] = s[t] - run;
    if (t == 255) totals[b] = s[t];
}

// ---------------------------------------------------------------------------
// scan phase 2+3 merged
// ---------------------------------------------------------------------------
__global__ __launch_bounds__(256) void scan_addtot_kernel(
    int* __restrict__ rp, int* __restrict__ cp, const int* __restrict__ totals)
{
    int b = blockIdx.x;
    int side = (b >= SCB) ? 1 : 0;
    int lb = side ? b - SCB : b;
    int t = threadIdx.x;

    __shared__ int s[128];
    if (t < 128) s[t] = (t < SCB) ? totals[side * SCB + t] : 0;
    __syncthreads();
#pragma unroll
    for (int off = 1; off < 128; off <<= 1) {
        int u = 0;
        if (t < 128 && t >= off) u = s[t - off];
        __syncthreads();
        if (t < 128) s[t] += u;
        __syncthreads();
    }
    int off = (lb == 0) ? 0 : s[lb - 1];
    int idx = lb * 256 + t;
    int* ptr = side ? cp : rp;
    if (idx < NN) ptr[idx] += off;
    if (b == 0   && t == 0) rp[NN] = NNZE;
    if (b == SCB && t == 0) cp[NN] = NNZE;
}

// ---------------------------------------------------------------------------
// atomic-free, XCD-partitioned scatter: pos = ptr[key] + P[chunk][key] + rank
// ---------------------------------------------------------------------------
__global__ __launch_bounds__(256) void scatter_rank_kernel(
    const int* __restrict__ rows, const int* __restrict__ cols,
    const float* __restrict__ vals,
    const unsigned short* __restrict__ rank_r, const unsigned short* __restrict__ rank_c,
    const int* __restrict__ histP,
    const int* __restrict__ rp, const int* __restrict__ cp,
    int2* __restrict__ csr_pair, int2* __restrict__ csc_pair)
{
    int part = blockIdx.x & (NPART - 1);
    int lo = part * PROWS, hi = lo + PROWS;
    int nb = gridDim.x >> 3;
    int bj = blockIdx.x >> 3;
    int stride = nb * 256;
    for (int e = bj * 256 + threadIdx.x; e < NNZE; e += stride) {
        int r = __builtin_nontemporal_load(rows + e);
        int c = __builtin_nontemporal_load(cols + e);
        float fv = __builtin_nontemporal_load(vals + e);
        int vb = __float_as_int(fv);
        int chunk = e / CH_E;
        if (r >= lo && r < hi) {
            int p = rp[r] + histP[(size_t)chunk * NN + r]
                  + (int)__builtin_nontemporal_load(rank_r + e);
            csr_pair[p] = make_int2(c, vb);
        }
        if (c >= lo && c < hi) {
            int q = cp[c] + histP[(size_t)(NCHUNK + chunk) * NN + c]
                  + (int)__builtin_nontemporal_load(rank_c + e);
            csc_pair[q] = make_int2(r, vb);
        }
    }
}

// ---------------------------------------------------------------------------
// FUSED layer-1: gather-SpMM D=64 -> swizzled LDS tile -> MFMA GEMM
// (K=128, DOUT=256). 32 rows/block; blockIdx.y = side (0: y1b, 1: z1b).
// LDS: sX 8KB + sW 32KB = 40KB -> 4 blocks/CU.
// ---------------------------------------------------------------------------
__global__ __launch_bounds__(256) void fused_l1_kernel(
    const int* __restrict__ rp, const int2* __restrict__ rpair,
    const int* __restrict__ cp, const int2* __restrict__ cpair,
    const unsigned short* __restrict__ lfb, const unsigned short* __restrict__ rfb,
    const unsigned short* __restrict__ Wt1, const float* __restrict__ bias1,
    unsigned short* __restrict__ y1b, unsigned short* __restrict__ z1b)
{
    __shared__ s8 sX[32 * 16];      // 32 rows x 16 chunks (K=128)
    __shared__ s8 sW[256 * 8];      // 256 cols x 8 chunks (K-chunk=64)
    unsigned int* sXu = (unsigned int*)sX;

    int side = blockIdx.y;
    const int*  ptr  = side ? cp    : rp;
    const int2* pair = side ? cpair : rpair;
    const unsigned int* gf = (const unsigned int*)(side ? lfb : rfb);
    const unsigned int* mf = (const unsigned int*)(side ? rfb : lfb);
    unsigned short* outp   = side ? z1b : y1b;

    const int t = threadIdx.x;
    const int rowbase = blockIdx.x * 32;

    // ---- phase 1: gather (half-wave per row, lane owns 2 feats) ----
    int hw = t >> 5;           // 0..7
    int l  = t & 31;
#pragma unroll
    for (int ri = 0; ri < 4; ++ri) {
        int rl = ri * 8 + hw;
        int w = rowbase + rl;
        float a0 = 0.f, a1 = 0.f;
        unsigned int m = 0;
        if (w < NN) {
            int e0 = ptr[w], e1 = ptr[w + 1];
            int e = e0;
            for (; e + 3 < e1; e += 4) {
                int2 p[4];
#pragma unroll
                for (int j = 0; j < 4; ++j) p[j] = nt_pair(&pair[e + j]);
                unsigned int z[4];
#pragma unroll
                for (int j = 0; j < 4; ++j) z[j] = gf[(size_t)p[j].x * 32 + l];
#pragma unroll
                for (int j = 0; j < 4; ++j) {
                    float v = __int_as_float(p[j].y);
                    a0 += v * bflo(z[j]);
                    a1 += v * bfhi(z[j]);
                }
            }
            for (; e < e1; ++e) {
                int2 p0 = nt_pair(&pair[e]);
                unsigned int z0 = gf[(size_t)p0.x * 32 + l];
                float v = __int_as_float(p0.y);
                a0 += v * bflo(z0);
                a1 += v * bfhi(z0);
            }
            m = mf[(size_t)w * 32 + l];
        }
        float m0 = a0 * bflo(m);
        float m1 = a1 * bfhi(m);
        unsigned int o0 = (unsigned int)f2bf(a0) | ((unsigned int)f2bf(a1) << 16);
        unsigned int o1 = (unsigned int)f2bf(m0) | ((unsigned int)f2bf(m1) << 16);
        int sw0 = (l >> 2) ^ (rl & 7);          // chunk 0..7 swizzled
        sXu[(((rl << 4) | sw0) << 2) | (l & 3)]       = o0;
        sXu[(((rl << 4) | 8 | sw0) << 2) | (l & 3)]   = o1;
    }
    __syncthreads();

    // ---- phase 2: GEMM ----
    const int wid = t >> 6;
    const int lane = t & 63;
    const int l15 = lane & 15;
    const int kg = lane >> 4;

    f4 acc[2][4] = {};
#pragma unroll
    for (int kc = 0; kc < 2; ++kc) {
        if (kc) __syncthreads();
#pragma unroll
        for (int it = 0; it < 8; ++it) {
            int ch = t + it * 256;
            int n = ch >> 3, c = ch & 7;
            sW[(n << 3) | (c ^ (n & 7))] = ((const s8*)Wt1)[n * 16 + kc * 8 + c];
        }
        __syncthreads();
#pragma unroll
        for (int ks = 0; ks < 2; ++ks) {
            int cch = ks * 4 + kg;
            s8 a[2], b[4];
#pragma unroll
            for (int fm = 0; fm < 2; ++fm) {
                int r0 = fm * 16 + l15;
                a[fm] = sX[(r0 << 4) | (kc * 8) | (cch ^ (r0 & 7))];
            }
#pragma unroll
            for (int fn = 0; fn < 4; ++fn) {
                int n0 = wid * 64 + fn * 16 + l15;
                b[fn] = sW[(n0 << 3) | (cch ^ (n0 & 7))];
            }
#pragma unroll
            for (int fm = 0; fm < 2; ++fm)
#pragma unroll
                for (int fn = 0; fn < 4; ++fn)
                    acc[fm][fn] = __builtin_amdgcn_mfma_f32_16x16x32_bf16(
                        a[fm], b[fn], acc[fm][fn], 0, 0, 0);
        }
    }

    // ---- epilogue: relu + bf16 store ----
#pragma unroll
    for (int fm = 0; fm < 2; ++fm) {
#pragma unroll
        for (int fn = 0; fn < 4; ++fn) {
            int col = wid * 64 + fn * 16 + l15;
            float bv = bias1[col];
#pragma unroll
            for (int j = 0; j < 4; ++j) {
                int row = rowbase + fm * 16 + kg * 4 + j;
                if (row < NN) {
                    unsigned short hv = f2bf(fmaxf(acc[fm][fn][j] + bv, 0.f));
                    unsigned short* q = outp + (size_t)row * 256 + col;
                    if (side == 0) __builtin_nontemporal_store(hv, q);  // y1b stream
                    else           *q = hv;                             // z1b cached
                }
            }
        }
    }
}

// ---------------------------------------------------------------------------
// FUSED layer-2: gather-SpMM D=256 on z1b (+y1b mult) -> swizzled LDS ->
// MFMA GEMM (K=512, DOUT=128) -> out f32 NT. 32 rows/block.
// LDS: sX 32KB + sW 16KB = 48KB -> 3 blocks/CU.
// ---------------------------------------------------------------------------
__global__ __launch_bounds__(256) void fused_l2_kernel(
    const int* __restrict__ ptr, const int2* __restrict__ pair,
    const unsigned short* __restrict__ z1b, const unsigned short* __restrict__ y1b,
    const unsigned short* __restrict__ Wt2, const float* __restrict__ bias2,
    float* __restrict__ out)
{
    __shared__ s8 sX[32 * 64];      // 32 rows x 64 chunks (K=512)
    __shared__ s8 sW[128 * 8];      // 128 cols x 8 chunks
    unsigned long long* sXu = (unsigned long long*)sX;

    const int t = threadIdx.x;
    const int rowbase = blockIdx.x * 32;
    const int wid = t >> 6;
    const int lane = t & 63;

    // ---- phase 1: gather (wave per row, lane owns 4 feats) ----
    const ushort4* Z = (const ushort4*)z1b;
#pragma unroll
    for (int ri = 0; ri < 8; ++ri) {
        int rl = ri * 4 + wid;
        int w = rowbase + rl;
        f4 acc = {0.f, 0.f, 0.f, 0.f};
        unsigned long long yu = 0;
        if (w < NN) {
            int e0 = ptr[w], e1 = ptr[w + 1];
            int e = e0;
            for (; e + 7 < e1; e += 8) {
                int2 p[8];
#pragma unroll
                for (int j = 0; j < 8; ++j) p[j] = nt_pair(&pair[e + j]);
                ushort4 z[8];
#pragma unroll
                for (int j = 0; j < 8; ++j) z[j] = Z[(size_t)p[j].x * 64 + lane];
#pragma unroll
                for (int j = 0; j < 8; ++j) {
                    float v = __int_as_float(p[j].y);
                    acc[0] += v * bf2f(z[j].x);
                    acc[1] += v * bf2f(z[j].y);
                    acc[2] += v * bf2f(z[j].z);
                    acc[3] += v * bf2f(z[j].w);
                }
            }
            for (; e < e1; ++e) {
                int2 p0 = nt_pair(&pair[e]);
                float v0 = __int_as_float(p0.y);
                ushort4 z0 = Z[(size_t)p0.x * 64 + lane];
                acc[0] += v0 * bf2f(z0.x);
                acc[1] += v0 * bf2f(z0.y);
                acc[2] += v0 * bf2f(z0.z);
                acc[3] += v0 * bf2f(z0.w);
            }
            yu = nt_u64(&((const ushort4*)y1b)[(size_t)w * 64 + lane]);
        }
        float y0 = bf2f((unsigned short)(yu));
        float y1 = bf2f((unsigned short)(yu >> 16));
        float y2 = bf2f((unsigned short)(yu >> 32));
        float y3 = bf2f((unsigned short)(yu >> 48));
        unsigned long long o0 =
            (unsigned long long)f2bf(acc[0])
          | ((unsigned long long)f2bf(acc[1]) << 16)
          | ((unsigned long long)f2bf(acc[2]) << 32)
          | ((unsigned long long)f2bf(acc[3]) << 48);
        unsigned long long o1 =
            (unsigned long long)f2bf(acc[0] * y0)
          | ((unsigned long long)f2bf(acc[1] * y1) << 16)
          | ((unsigned long long)f2bf(acc[2] * y2) << 32)
          | ((unsigned long long)f2bf(acc[3] * y3) << 48);
        int ch0 = lane >> 1;                         // 0..31
        int sw0 = (ch0 & ~7) | ((ch0 & 7) ^ (rl & 7));
        sXu[(((rl << 6) | sw0) << 1) | (lane & 1)]        = o0;
        sXu[(((rl << 6) | 32 | sw0) << 1) | (lane & 1)]   = o1;
    }
    __syncthreads();

    // ---- phase 2: GEMM K=512 ----
    const int l15 = lane & 15;
    const int kg = lane >> 4;

    f4 acc[2][2] = {};
#pragma unroll
    for (int kc = 0; kc < 8; ++kc) {
        if (kc) __syncthreads();
#pragma unroll
        for (int it = 0; it < 4; ++it) {
            int ch = t + it * 256;
            int n = ch >> 3, c = ch & 7;
            sW[(n << 3) | (c ^ (n & 7))] = ((const s8*)Wt2)[n * 64 + kc * 8 + c];
        }
        __syncthreads();
#pragma unroll
        for (int ks = 0; ks < 2; ++ks) {
            int cch = ks * 4 + kg;
            s8 a[2], b[2];
#pragma unroll
            for (int fm = 0; fm < 2; ++fm) {
                int r0 = fm * 16 + l15;
                a[fm] = sX[(r0 << 6) | (kc * 8) | (cch ^ (r0 & 7))];
            }
#pragma unroll
            for (int fn = 0; fn < 2; ++fn) {
                int n0 = wid * 32 + fn * 16 + l15;
                b[fn] = sW[(n0 << 3) | (cch ^ (n0 & 7))];
            }
#pragma unroll
            for (int fm = 0; fm < 2; ++fm)
#pragma unroll
                for (int fn = 0; fn < 2; ++fn)
                    acc[fm][fn] = __builtin_amdgcn_mfma_f32_16x16x32_bf16(
                        a[fm], b[fn], acc[fm][fn], 0, 0, 0);
        }
    }

    // ---- epilogue: relu + f32 NT store ----
#pragma unroll
    for (int fm = 0; fm < 2; ++fm) {
#pragma unroll
        for (int fn = 0; fn < 2; ++fn) {
            int col = wid * 32 + fn * 16 + l15;
            float bv = bias2[col];
#pragma unroll
            for (int j = 0; j < 4; ++j) {
                int row = rowbase + fm * 16 + kg * 4 + j;
                if (row < NN) {
                    float v = fmaxf(acc[fm][fn][j] + bv, 0.f);
                    __builtin_nontemporal_store(v, out + (size_t)row * 128 + col);
                }
            }
        }
    }
}

// ---------------------------------------------------------------------------
extern "C" void kernel_launch(void* const* d_in, const int* in_sizes, int n_in,
                              void* d_out, int out_size, void* d_ws, size_t ws_size,
                              hipStream_t stream)
{
    const float* l_feat = (const float*)d_in[0];
    const float* r_feat = (const float*)d_in[1];
    const int*   rows   = (const int*)  d_in[2];
    const int*   cols   = (const int*)  d_in[3];
    const float* vals   = (const float*)d_in[4];
    const float* W1     = (const float*)d_in[5];
    const float* b1     = (const float*)d_in[6];
    const float* W2     = (const float*)d_in[7];
    const float* b2     = (const float*)d_in[8];
    const float* W3     = (const float*)d_in[9];
    const float* b3     = (const float*)d_in[10];
    const float* W4     = (const float*)d_in[11];
    const float* b4     = (const float*)d_in[12];
    float* out = (float*)d_out;

    // ---- workspace carve ----
    char* p = (char*)d_ws;
    unsigned short* z1b = (unsigned short*)p; p += (size_t)NN * 256 * 2;
    unsigned short* y1b = (unsigned short*)p; p += (size_t)NN * 256 * 2;
    unsigned short* lfb = (unsigned short*)p; p += (size_t)NN * 64 * 2;
    unsigned short* rfb = (unsigned short*)p; p += (size_t)NN * 64 * 2;
    int* histP    = (int*)p; p += (size_t)2 * NCHUNK * NN * 4;   // 7.68 MB
    int* totals   = (int*)p; p += 256 * 4;
    unsigned short* Wt1 = (unsigned short*)p; p += 32768 * 2;
    unsigned short* Wt2 = (unsigned short*)p; p += 65536 * 2;
    float* bias1 = (float*)p; p += 256 * 4;
    float* bias2 = (float*)p; p += 128 * 4;
    int*   row_ptr  = (int*)p; p += (size_t)(NN + 4) * 4;
    int*   col_ptr  = (int*)p; p += (size_t)(NN + 4) * 4;
    int2*  csr_pair = (int2*)p; p += (size_t)NNZE * 8;
    int2*  csc_pair = (int2*)p; p += (size_t)NNZE * 8;
    unsigned short* rank_r = (unsigned short*)p; p += (size_t)NNZE * 2;
    unsigned short* rank_c = (unsigned short*)p; p += (size_t)NNZE * 2;

    // 1. fused prep
    prep_kernel<<<(PREP_W1 + 255) / 256, 256, 0, stream>>>(
        l_feat, r_feat, W1, W2, W3, W4, b1, b2, b3, b4,
        lfb, rfb, Wt1, Wt2, bias1, bias2);

    // 2. LDS-histogram count + local rank
    count_rank_kernel<<<128, 256, 0, stream>>>(rows, cols, histP, rank_r, rank_c);

    // 3. scan
    scanP_kernel<<<2 * SCB, 256, 0, stream>>>(histP, row_ptr, col_ptr, totals);
    scan_addtot_kernel<<<2 * SCB, 256, 0, stream>>>(row_ptr, col_ptr, totals);

    // 4. atomic-free XCD-partitioned scatter
    scatter_rank_kernel<<<1024, 256, 0, stream>>>(
        rows, cols, vals, rank_r, rank_c, histP, row_ptr, col_ptr, csr_pair, csc_pair);

    // 5. fused layer-1: gather D=64 + GEMM -> y1b / z1b (no X1/X2 buffers)
    {
        dim3 grid((NN + 31) / 32, 2);
        fused_l1_kernel<<<grid, 256, 0, stream>>>(
            row_ptr, csr_pair, col_ptr, csc_pair, lfb, rfb, Wt1, bias1, y1b, z1b);
    }

    // 6. fused layer-2: gather D=256 + GEMM -> out (no X3 buffer)
    {
        dim3 grid((NN + 31) / 32);
        fused_l2_kernel<<<grid, 256, 0, stream>>>(
            row_ptr, csr_pair, z1b, y1b, Wt2, bias2, out);
    }
}

// Round 11
// 195.185 us; speedup vs baseline: 1.2100x; 1.2100x over previous
//
#include <hip/hip_runtime.h>

#define NN     30000
#define NNZE   480000
#define NPART  8
#define PROWS  (NN / NPART)      // 3750, exact
#define NCHUNK 64
#define CH_E   (NNZE / NCHUNK)   // 7500, exact
#define HBIN   (NN / 2)          // 15000 bins per half (60000 B LDS)
#define SCB    118               // ceil(30000/256)

using s8 = __attribute__((ext_vector_type(8))) short;  // 8 bf16 = 4 VGPRs
using f4 = __attribute__((ext_vector_type(4))) float;

__device__ __forceinline__ unsigned short f2bf(float x) {
    unsigned int u = __float_as_uint(x);
    u += 0x7fff + ((u >> 16) & 1);          // round-to-nearest-even
    return (unsigned short)(u >> 16);
}
__device__ __forceinline__ float bf2f(unsigned short h) {
    return __uint_as_float(((unsigned int)h) << 16);
}
__device__ __forceinline__ float bflo(unsigned int z) {
    return __uint_as_float(z << 16);
}
__device__ __forceinline__ float bfhi(unsigned int z) {
    return __uint_as_float(z & 0xffff0000u);
}
__device__ __forceinline__ int2 nt_pair(const int2* p) {
    long long v = __builtin_nontemporal_load((const long long*)p);
    int2 r; r.x = (int)(unsigned int)v; r.y = (int)(v >> 32); return r;
}
__device__ __forceinline__ unsigned long long nt_u64(const void* p) {
    return __builtin_nontemporal_load((const unsigned long long*)p);
}

// ---------------------------------------------------------------------------
// fused prep: feat->bf16 conversion, weight transpose->bf16, bias sums
// ---------------------------------------------------------------------------
#define FEAT4   (NN * 64 / 4)              // 480000 float4 groups per feat
#define PREP_W0 (2 * FEAT4)                // 960000
#define PREP_W1 (PREP_W0 + 98688)          // wprep range
__global__ __launch_bounds__(256) void prep_kernel(
    const float* __restrict__ lf, const float* __restrict__ rf,
    const float* __restrict__ W1, const float* __restrict__ W2,
    const float* __restrict__ W3, const float* __restrict__ W4,
    const float* __restrict__ b1, const float* __restrict__ b2,
    const float* __restrict__ b3, const float* __restrict__ b4,
    unsigned short* __restrict__ lfb, unsigned short* __restrict__ rfb,
    unsigned short* __restrict__ Wt1, unsigned short* __restrict__ Wt2,
    float* __restrict__ bias1, float* __restrict__ bias2)
{
    int i = blockIdx.x * 256 + threadIdx.x;
    if (i < PREP_W0) {
        const float* src = (i < FEAT4) ? lf : rf;
        unsigned short* dst = (i < FEAT4) ? lfb : rfb;
        int j = (i < FEAT4) ? i : i - FEAT4;
        float4 v = ((const float4*)src)[j];
        ushort4 o;
        o.x = f2bf(v.x); o.y = f2bf(v.y); o.z = f2bf(v.z); o.w = f2bf(v.w);
        ((ushort4*)dst)[j] = o;
    } else if (i < PREP_W1) {
        int j = i - PREP_W0;
        if (j < 32768) {                       // Wt1: [256][128]
            int n = j >> 7, k = j & 127;
            float v = (k < 64) ? W1[(size_t)k * 256 + n] : W2[(size_t)(k - 64) * 256 + n];
            Wt1[j] = f2bf(v);
        } else if (j < 32768 + 65536) {        // Wt2: [128][512]
            int q = j - 32768;
            int n = q >> 9, k = q & 511;
            float v = (k < 256) ? W3[(size_t)k * 128 + n] : W4[(size_t)(k - 256) * 128 + n];
            Wt2[q] = f2bf(v);
        } else if (j < 98304 + 256) {
            int n = j - 98304; bias1[n] = b1[n] + b2[n];
        } else if (j < 98560 + 128) {
            int n = j - 98560; bias2[n] = b3[n] + b4[n];
        }
    }
}

// ---------------------------------------------------------------------------
// LDS-histogram count + local rank. 256 blocks = side(2) x chunk(64) x half(2)
// -> full CU coverage (was 128 blocks = half the GPU idle).
// ---------------------------------------------------------------------------
__global__ __launch_bounds__(256) void count_rank_kernel(
    const int* __restrict__ rows, const int* __restrict__ cols,
    int* __restrict__ histP,
    unsigned short* __restrict__ rank_r, unsigned short* __restrict__ rank_c)
{
    int b = blockIdx.x;
    int side  = b >> 7;
    int chunk = (b & 127) >> 1;
    int half  = b & 1;
    const int* keys = side ? cols : rows;
    unsigned short* rank = side ? rank_c : rank_r;
    int binlo = half * HBIN;

    __shared__ int h[HBIN];                  // 60000 B
    for (int i = threadIdx.x; i < HBIN; i += 256) h[i] = 0;
    __syncthreads();

    int e0 = chunk * CH_E;
    for (int e = e0 + threadIdx.x; e < e0 + CH_E; e += 256) {
        int k = __builtin_nontemporal_load(keys + e) - binlo;
        if ((unsigned)k < (unsigned)HBIN)
            rank[e] = (unsigned short)atomicAdd(&h[k], 1);
    }
    __syncthreads();

    int* dst = histP + ((size_t)(side * NCHUNK + chunk)) * NN + binlo;
    for (int i = threadIdx.x; i < HBIN; i += 256)
        __builtin_nontemporal_store(h[i], dst + i);
}

// ---------------------------------------------------------------------------
// scanP: per-bin exclusive prefix over the 64 chunk histograms (in place),
// then local 256-wide scan -> rp/cp + totals
// ---------------------------------------------------------------------------
__global__ __launch_bounds__(256) void scanP_kernel(
    int* __restrict__ histP,
    int* __restrict__ rp, int* __restrict__ cp, int* __restrict__ totals)
{
    int b = blockIdx.x;
    int side = (b >= SCB) ? 1 : 0;
    int lb = side ? b - SCB : b;
    int t = threadIdx.x;
    int bin = lb * 256 + t;

    int run = 0;
    if (bin < NN) {
        int* base = histP + (size_t)side * NCHUNK * NN + bin;
#pragma unroll 4
        for (int c = 0; c < NCHUNK; ++c) {
            int v = base[(size_t)c * NN];
            base[(size_t)c * NN] = run;
            run += v;
        }
    }
    __shared__ int s[256];
    s[t] = run;
    __syncthreads();
#pragma unroll
    for (int off = 1; off < 256; off <<= 1) {
        int u = (t >= off) ? s[t - off] : 0;
        __syncthreads();
        s[t] += u;
        __syncthreads();
    }
    if (bin < NN) (side ? cp : rp)[bin] = s[t] - run;
    if (t == 255) totals[b] = s[t];
}

// ---------------------------------------------------------------------------
// scan phase 2+3 merged
// ---------------------------------------------------------------------------
__global__ __launch_bounds__(256) void scan_addtot_kernel(
    int* __restrict__ rp, int* __restrict__ cp, const int* __restrict__ totals)
{
    int b = blockIdx.x;
    int side = (b >= SCB) ? 1 : 0;
    int lb = side ? b - SCB : b;
    int t = threadIdx.x;

    __shared__ int s[128];
    if (t < 128) s[t] = (t < SCB) ? totals[side * SCB + t] : 0;
    __syncthreads();
#pragma unroll
    for (int off = 1; off < 128; off <<= 1) {
        int u = 0;
        if (t < 128 && t >= off) u = s[t - off];
        __syncthreads();
        if (t < 128) s[t] += u;
        __syncthreads();
    }
    int off = (lb == 0) ? 0 : s[lb - 1];
    int idx = lb * 256 + t;
    int* ptr = side ? cp : rp;
    if (idx < NN) ptr[idx] += off;
    if (b == 0   && t == 0) rp[NN] = NNZE;
    if (b == SCB && t == 0) cp[NN] = NNZE;
}

// ---------------------------------------------------------------------------
// atomic-free, XCD-partitioned scatter: pos = ptr[key] + P[chunk][key] + rank
// ---------------------------------------------------------------------------
__global__ __launch_bounds__(256) void scatter_rank_kernel(
    const int* __restrict__ rows, const int* __restrict__ cols,
    const float* __restrict__ vals,
    const unsigned short* __restrict__ rank_r, const unsigned short* __restrict__ rank_c,
    const int* __restrict__ histP,
    const int* __restrict__ rp, const int* __restrict__ cp,
    int2* __restrict__ csr_pair, int2* __restrict__ csc_pair)
{
    int part = blockIdx.x & (NPART - 1);
    int lo = part * PROWS, hi = lo + PROWS;
    int nb = gridDim.x >> 3;
    int bj = blockIdx.x >> 3;
    int stride = nb * 256;
    for (int e = bj * 256 + threadIdx.x; e < NNZE; e += stride) {
        int r = __builtin_nontemporal_load(rows + e);
        int c = __builtin_nontemporal_load(cols + e);
        float fv = __builtin_nontemporal_load(vals + e);
        int vb = __float_as_int(fv);
        int chunk = e / CH_E;
        if (r >= lo && r < hi) {
            int p = rp[r] + histP[(size_t)chunk * NN + r]
                  + (int)__builtin_nontemporal_load(rank_r + e);
            csr_pair[p] = make_int2(c, vb);
        }
        if (c >= lo && c < hi) {
            int q = cp[c] + histP[(size_t)(NCHUNK + chunk) * NN + c]
                  + (int)__builtin_nontemporal_load(rank_c + e);
            csc_pair[q] = make_int2(r, vb);
        }
    }
}

// ---------------------------------------------------------------------------
// gather-SpMM D=64: half-wave per row, 8 rows/block; LDS-staged pair segment,
// 8-deep inner unroll. NT X stores (stream-once).
// ---------------------------------------------------------------------------
#define G64CAP 768
__global__ __launch_bounds__(256) void gather64_x_kernel(
    const int* __restrict__ rp, const int2* __restrict__ rpair,
    const int* __restrict__ cp, const int2* __restrict__ cpair,
    const unsigned short* __restrict__ lfb, const unsigned short* __restrict__ rfb,
    unsigned short* __restrict__ X1, unsigned short* __restrict__ X2)
{
    int side = blockIdx.y;
    const int*  ptr  = side ? cp    : rp;
    const int2* pair = side ? cpair : rpair;
    const unsigned int* gf = (const unsigned int*)(side ? lfb : rfb);
    const unsigned int* mf = (const unsigned int*)(side ? rfb : lfb);
    unsigned int* X = (unsigned int*)(side ? X2 : X1);

    __shared__ int2 sp[G64CAP];
    int w0 = blockIdx.x * 8;
    int e0b = ptr[w0];
    int nseg = ptr[w0 + 8] - e0b;
    for (int i = threadIdx.x; i < nseg && i < G64CAP; i += 256)
        sp[i] = nt_pair(&pair[e0b + i]);
    __syncthreads();

    int w = w0 + (threadIdx.x >> 5);
    int l = threadIdx.x & 31;
    int ea = ptr[w] - e0b, eb = ptr[w + 1] - e0b;
    float a0 = 0.f, a1 = 0.f;
    int e = ea;
    for (; e + 7 < eb; e += 8) {
        int2 p[8];
#pragma unroll
        for (int j = 0; j < 8; ++j)
            p[j] = (e + j < G64CAP) ? sp[e + j] : nt_pair(&pair[e0b + e + j]);
        unsigned int z[8];
#pragma unroll
        for (int j = 0; j < 8; ++j) z[j] = gf[(size_t)p[j].x * 32 + l];
#pragma unroll
        for (int j = 0; j < 8; ++j) {
            float v = __int_as_float(p[j].y);
            a0 += v * bflo(z[j]);
            a1 += v * bfhi(z[j]);
        }
    }
    for (; e < eb; ++e) {
        int2 p0 = (e < G64CAP) ? sp[e] : nt_pair(&pair[e0b + e]);
        unsigned int z0 = gf[(size_t)p0.x * 32 + l];
        float v = __int_as_float(p0.y);
        a0 += v * bflo(z0);
        a1 += v * bfhi(z0);
    }
    unsigned int m = mf[(size_t)w * 32 + l];
    float m0 = a0 * bflo(m);
    float m1 = a1 * bfhi(m);
    unsigned int o0 = (unsigned int)f2bf(a0) | ((unsigned int)f2bf(a1) << 16);
    unsigned int o1 = (unsigned int)f2bf(m0) | ((unsigned int)f2bf(m1) << 16);
    __builtin_nontemporal_store(o0, &X[(size_t)w * 64 + l]);
    __builtin_nontemporal_store(o1, &X[(size_t)w * 64 + 32 + l]);
}

// ---------------------------------------------------------------------------
// gather-SpMM D=256, wave-per-row: 16-deep register pair prefetch so a full
// average row (16 edges) has all gathers in flight in one round trip.
// ---------------------------------------------------------------------------
__global__ __launch_bounds__(256) void gather256_x_kernel(
    const int* __restrict__ ptr, const int2* __restrict__ pair,
    const unsigned short* __restrict__ z1b, const unsigned short* __restrict__ y1b,
    unsigned short* __restrict__ X3)
{
    int w    = blockIdx.x * 4 + (threadIdx.x >> 6);
    int lane = threadIdx.x & 63;
    int e0 = ptr[w], e1 = ptr[w + 1];
    const ushort4* Z = (const ushort4*)z1b;   // row stride 64 ushort4
    f4 acc = {0.f, 0.f, 0.f, 0.f};
    int e = e0;
    for (; e + 15 < e1; e += 16) {
        int2 p[16];
#pragma unroll
        for (int j = 0; j < 16; ++j) p[j] = nt_pair(&pair[e + j]);
        ushort4 z[16];
#pragma unroll
        for (int j = 0; j < 16; ++j) z[j] = Z[(size_t)p[j].x * 64 + lane];
#pragma unroll
        for (int j = 0; j < 16; ++j) {
            float v = __int_as_float(p[j].y);
            acc[0] += v * bf2f(z[j].x);
            acc[1] += v * bf2f(z[j].y);
            acc[2] += v * bf2f(z[j].z);
            acc[3] += v * bf2f(z[j].w);
        }
    }
    for (; e + 3 < e1; e += 4) {
        int2 p[4];
#pragma unroll
        for (int j = 0; j < 4; ++j) p[j] = nt_pair(&pair[e + j]);
        ushort4 z[4];
#pragma unroll
        for (int j = 0; j < 4; ++j) z[j] = Z[(size_t)p[j].x * 64 + lane];
#pragma unroll
        for (int j = 0; j < 4; ++j) {
            float v = __int_as_float(p[j].y);
            acc[0] += v * bf2f(z[j].x);
            acc[1] += v * bf2f(z[j].y);
            acc[2] += v * bf2f(z[j].z);
            acc[3] += v * bf2f(z[j].w);
        }
    }
    for (; e < e1; ++e) {
        int2 p0 = nt_pair(&pair[e]);
        float v0 = __int_as_float(p0.y);
        ushort4 z0 = Z[(size_t)p0.x * 64 + lane];
        acc[0] += v0 * bf2f(z0.x);
        acc[1] += v0 * bf2f(z0.y);
        acc[2] += v0 * bf2f(z0.z);
        acc[3] += v0 * bf2f(z0.w);
    }
    unsigned long long yu = nt_u64(&((const ushort4*)y1b)[(size_t)w * 64 + lane]);
    float y0 = bf2f((unsigned short)(yu));
    float y1 = bf2f((unsigned short)(yu >> 16));
    float y2 = bf2f((unsigned short)(yu >> 32));
    float y3 = bf2f((unsigned short)(yu >> 48));
    unsigned long long o0 =
        (unsigned long long)f2bf(acc[0])
      | ((unsigned long long)f2bf(acc[1]) << 16)
      | ((unsigned long long)f2bf(acc[2]) << 32)
      | ((unsigned long long)f2bf(acc[3]) << 48);
    unsigned long long o1 =
        (unsigned long long)f2bf(acc[0] * y0)
      | ((unsigned long long)f2bf(acc[1] * y1) << 16)
      | ((unsigned long long)f2bf(acc[2] * y2) << 32)
      | ((unsigned long long)f2bf(acc[3] * y3) << 48);
    unsigned long long* X3u = (unsigned long long*)X3;
    __builtin_nontemporal_store(o0, &X3u[(size_t)w * 128 + lane]);
    __builtin_nontemporal_store(o1, &X3u[(size_t)w * 128 + 64 + lane]);
}

// ---------------------------------------------------------------------------
// MFMA GEMM: out = relu(X[NN][K] @ Wt^T + bias), Wt [DOUT][K] bf16.
// ---------------------------------------------------------------------------
template<int K, int DOUT, bool OUT_BF16, bool NT_A, bool NT_B>
__global__ __launch_bounds__(256) void mfma_gemm_kernel(
    const unsigned short* Xa, const unsigned short* Xb,
    const unsigned short* __restrict__ Wt, const float* __restrict__ bias,
    void* outa, void* outb)
{
    constexpr int WC = DOUT / 4;       // cols per wave (64 or 32)
    constexpr int FN = WC / 16;        // 4 or 2
    __shared__ s8 sX[64 * 8];          // [row][chunk], chunk ^= row&7
    __shared__ s8 sW[DOUT * 8];

    const unsigned short* X = blockIdx.y ? Xb : Xa;
    void* outv              = blockIdx.y ? outb : outa;
    const bool nt_out       = blockIdx.y ? NT_B : NT_A;

    const int t       = threadIdx.x;
    const int rowbase = blockIdx.x * 64;
    const int wid     = t >> 6;
    const int lane    = t & 63;
    const int l15     = lane & 15;
    const int kg      = lane >> 4;

    f4 acc[4][FN] = {};

    for (int kc = 0; kc < K; kc += 64) {
#pragma unroll
        for (int it = 0; it < 2; ++it) {
            int ch = t + it * 256;
            int r = ch >> 3, c = ch & 7;
            int row = rowbase + r;
            s8 v = {};
            if (row < NN)
                v = __builtin_nontemporal_load(((const s8*)X) + ((size_t)row * K + kc) / 8 + c);
            sX[(r << 3) | (c ^ (r & 7))] = v;
        }
#pragma unroll
        for (int it = 0; it < DOUT / 32; ++it) {
            int ch = t + it * 256;
            int n = ch >> 3, c = ch & 7;
            sW[(n << 3) | (c ^ (n & 7))] = ((const s8*)Wt)[((size_t)n * K + kc) / 8 + c];
        }
        __syncthreads();

#pragma unroll
        for (int ks = 0; ks < 2; ++ks) {
            int cch = ks * 4 + kg;
            s8 a[4], b[FN];
#pragma unroll
            for (int fm = 0; fm < 4; ++fm) {
                int r0 = fm * 16 + l15;
                a[fm] = sX[(r0 << 3) | (cch ^ (r0 & 7))];
            }
#pragma unroll
            for (int fn = 0; fn < FN; ++fn) {
                int n0 = wid * WC + fn * 16 + l15;
                b[fn] = sW[(n0 << 3) | (cch ^ (n0 & 7))];
            }
#pragma unroll
            for (int fm = 0; fm < 4; ++fm)
#pragma unroll
                for (int fn = 0; fn < FN; ++fn)
                    acc[fm][fn] = __builtin_amdgcn_mfma_f32_16x16x32_bf16(
                        a[fm], b[fn], acc[fm][fn], 0, 0, 0);
        }
        __syncthreads();
    }

    // epilogue: C/D layout col=lane&15, row=kg*4+j
#pragma unroll
    for (int fm = 0; fm < 4; ++fm) {
#pragma unroll
        for (int fn = 0; fn < FN; ++fn) {
            int col = wid * WC + fn * 16 + l15;
            float bv = bias[col];
#pragma unroll
            for (int j = 0; j < 4; ++j) {
                int row = rowbase + fm * 16 + kg * 4 + j;
                if (row < NN) {
                    float v = fmaxf(acc[fm][fn][j] + bv, 0.f);
                    if constexpr (OUT_BF16) {
                        unsigned short* q = (unsigned short*)outv + (size_t)row * DOUT + col;
                        if (nt_out) __builtin_nontemporal_store(f2bf(v), q);
                        else        *q = f2bf(v);
                    } else {
                        float* q = (float*)outv + (size_t)row * DOUT + col;
                        if (nt_out) __builtin_nontemporal_store(v, q);
                        else        *q = v;
                    }
                }
            }
        }
    }
}

// ---------------------------------------------------------------------------
extern "C" void kernel_launch(void* const* d_in, const int* in_sizes, int n_in,
                              void* d_out, int out_size, void* d_ws, size_t ws_size,
                              hipStream_t stream)
{
    const float* l_feat = (const float*)d_in[0];
    const float* r_feat = (const float*)d_in[1];
    const int*   rows   = (const int*)  d_in[2];
    const int*   cols   = (const int*)  d_in[3];
    const float* vals   = (const float*)d_in[4];
    const float* W1     = (const float*)d_in[5];
    const float* b1     = (const float*)d_in[6];
    const float* W2     = (const float*)d_in[7];
    const float* b2     = (const float*)d_in[8];
    const float* W3     = (const float*)d_in[9];
    const float* b3     = (const float*)d_in[10];
    const float* W4     = (const float*)d_in[11];
    const float* b4     = (const float*)d_in[12];
    float* out = (float*)d_out;

    // ---- workspace carve ----
    char* p = (char*)d_ws;
    unsigned short* X1  = (unsigned short*)p; p += (size_t)NN * 128 * 2;
    unsigned short* X2  = (unsigned short*)p; p += (size_t)NN * 128 * 2;
    unsigned short* X3  = (unsigned short*)p; p += (size_t)NN * 512 * 2;
    unsigned short* z1b = (unsigned short*)p; p += (size_t)NN * 256 * 2;
    unsigned short* y1b = (unsigned short*)p; p += (size_t)NN * 256 * 2;
    unsigned short* lfb = (unsigned short*)p; p += (size_t)NN * 64 * 2;
    unsigned short* rfb = (unsigned short*)p; p += (size_t)NN * 64 * 2;
    int* histP    = (int*)p; p += (size_t)2 * NCHUNK * NN * 4;   // 15.36 MB
    int* totals   = (int*)p; p += 256 * 4;
    unsigned short* Wt1 = (unsigned short*)p; p += 32768 * 2;
    unsigned short* Wt2 = (unsigned short*)p; p += 65536 * 2;
    float* bias1 = (float*)p; p += 256 * 4;
    float* bias2 = (float*)p; p += 128 * 4;
    int*   row_ptr  = (int*)p; p += (size_t)(NN + 4) * 4;
    int*   col_ptr  = (int*)p; p += (size_t)(NN + 4) * 4;
    int2*  csr_pair = (int2*)p; p += (size_t)NNZE * 8;
    int2*  csc_pair = (int2*)p; p += (size_t)NNZE * 8;
    unsigned short* rank_r = (unsigned short*)p; p += (size_t)NNZE * 2;
    unsigned short* rank_c = (unsigned short*)p; p += (size_t)NNZE * 2;

    // 1. fused prep
    prep_kernel<<<(PREP_W1 + 255) / 256, 256, 0, stream>>>(
        l_feat, r_feat, W1, W2, W3, W4, b1, b2, b3, b4,
        lfb, rfb, Wt1, Wt2, bias1, bias2);

    // 2. LDS-histogram count + local rank (256 blocks -> full CU coverage)
    count_rank_kernel<<<256, 256, 0, stream>>>(rows, cols, histP, rank_r, rank_c);

    // 3. scan
    scanP_kernel<<<2 * SCB, 256, 0, stream>>>(histP, row_ptr, col_ptr, totals);
    scan_addtot_kernel<<<2 * SCB, 256, 0, stream>>>(row_ptr, col_ptr, totals);

    // 4. atomic-free XCD-partitioned scatter
    scatter_rank_kernel<<<1024, 256, 0, stream>>>(
        rows, cols, vals, rank_r, rank_c, histP, row_ptr, col_ptr, csr_pair, csc_pair);

    // 5. gather-SpMM D=64, both directions
    {
        dim3 grid(NN / 8, 2);
        gather64_x_kernel<<<grid, 256, 0, stream>>>(
            row_ptr, csr_pair, col_ptr, csc_pair, lfb, rfb, X1, X2);
    }

    // 6. layer-1 MFMA GEMMs (y1b NT, z1b cached for the upcoming gather)
    {
        dim3 grid((NN + 63) / 64, 2);
        mfma_gemm_kernel<128, 256, true, true, false><<<grid, 256, 0, stream>>>(
            X1, X2, Wt1, bias1, y1b, z1b);
    }

    // 7. gather-SpMM D=256 (16-deep prefetch)
    gather256_x_kernel<<<NN / 4, 256, 0, stream>>>(row_ptr, csr_pair, z1b, y1b, X3);

    // 8. layer-2 MFMA GEMM -> output (f32, NT)
    {
        dim3 grid((NN + 63) / 64, 1);
        mfma_gemm_kernel<512, 128, false, true, true><<<grid, 256, 0, stream>>>(
            X3, X3, Wt2, bias2, out, out);
    }
}